// Round 1
// baseline (43085.822 us; speedup 1.0000x reference)
//
#include <hip/hip_runtime.h>
#include <hip/hip_bf16.h>
#include <cstdint>

#define B_ 64
#define T_ 1024
#define D_ 512
#define H_ 1024
// 4H = 4096

typedef unsigned short u16;
typedef __attribute__((ext_vector_type(4))) float f32x4;
typedef __attribute__((ext_vector_type(8))) short bf16x8;   // 8 bf16 in 4 VGPRs
typedef __attribute__((ext_vector_type(8))) u16 u16x8;

__device__ __forceinline__ u16 f2bf(float f) {
    uint32_t u = __float_as_uint(f);
    uint32_t r = (u + 0x7FFFu + ((u >> 16) & 1u)) >> 16;   // RNE
    return (u16)r;
}
__device__ __forceinline__ float sigm(float x)  { return 1.f / (1.f + __expf(-x)); }
__device__ __forceinline__ float ftanh(float x) { return 1.f - 2.f / (__expf(2.f * x) + 1.f); }

// ---- x fp32 -> bf16 (vectorized) ----
__global__ __launch_bounds__(256) void pack_x(const float* __restrict__ x, u16* __restrict__ xb) {
    size_t i = ((size_t)blockIdx.x * 256 + threadIdx.x) * 8;
    float4 a = *reinterpret_cast<const float4*>(x + i);
    float4 c = *reinterpret_cast<const float4*>(x + i + 4);
    u16x8 v;
    v[0] = f2bf(a.x); v[1] = f2bf(a.y); v[2] = f2bf(a.z); v[3] = f2bf(a.w);
    v[4] = f2bf(c.x); v[5] = f2bf(c.y); v[6] = f2bf(c.z); v[7] = f2bf(c.w);
    *reinterpret_cast<u16x8*>(xb + i) = v;
}

// ---- W [K][N] fp32 -> WT [N][dstLD] bf16 at column offset koff ----
__global__ __launch_bounds__(256) void transp(const float* __restrict__ src, u16* __restrict__ dst,
                                              int N, int dstLD, int koff) {
    __shared__ float tile[32][33];
    int n0 = blockIdx.x * 32, k0 = blockIdx.y * 32;
    int tx = threadIdx.x, ty = threadIdx.y;   // 32 x 8
    #pragma unroll
    for (int i = 0; i < 4; ++i)
        tile[ty + 8 * i][tx] = src[(size_t)(k0 + ty + 8 * i) * N + n0 + tx];
    __syncthreads();
    #pragma unroll
    for (int i = 0; i < 4; ++i) {
        int n = n0 + ty + 8 * i;
        dst[(size_t)n * dstLD + koff + k0 + tx] = f2bf(tile[tx][ty + 8 * i]);
    }
}

// ---- one pipeline phase: layer0 @ t=p (blocks 0..63), layer1 @ t=p-1 (blocks 64..127) ----
// L0: gates0 = [x_t ; h0_prev] @ [Wx0 ; Wh0]  (K = 512+1024)
// L1: gates1 = [h0_t' ; h1_prev] @ [Wx1 ; Wh1] (K = 2048)
__global__ __launch_bounds__(256) void lstm_phase(
    const u16* __restrict__ xb, const u16* __restrict__ Wx0T,
    const u16* __restrict__ WT0, const u16* __restrict__ WT1,
    const float* __restrict__ b0, const float* __restrict__ b1,
    u16* __restrict__ h0b, u16* __restrict__ h1b,
    float* __restrict__ c0, float* __restrict__ c1,
    float* __restrict__ out, int p)
{
    const int wave = threadIdx.x >> 6;
    const int lane = threadIdx.x & 63;
    const int r16 = lane & 15;       // A row in tile / D col
    const int kg  = lane >> 4;       // k-octet group / D row-group
    const int bid = blockIdx.x;
    const size_t BTH = (size_t)B_ * T_ * H_;
    const int BH = B_ * H_;

    f32x4 acc[4] = {{0,0,0,0},{0,0,0,0},{0,0,0,0},{0,0,0,0}};

    if (bid < 64) {
        if (p >= T_) return;
        const int hc = bid * 16;                      // h0 columns [hc, hc+16)
        const u16* h0prev = h0b + ((p + 1) & 1) * BH; // h0[p-1]
        u16*       h0cur  = h0b + (p & 1) * BH;       // h0[p]
        const int brow = wave * 16 + r16;             // batch row loaded by this lane

        for (int ks = 0; ks < 48; ++ks) {
            const int kk = ks * 32 + kg * 8;          // k within [0,1536)
            bf16x8 a;
            if (ks < 16) a = *reinterpret_cast<const bf16x8*>(xb + ((size_t)brow * T_ + p) * D_ + kk);
            else         a = *reinterpret_cast<const bf16x8*>(h0prev + brow * H_ + (kk - 512));
            #pragma unroll
            for (int q = 0; q < 4; ++q) {             // gate i,f,g,o
                const int n = q * H_ + hc + r16;
                bf16x8 bf;
                if (ks < 16) bf = *reinterpret_cast<const bf16x8*>(Wx0T + (size_t)n * 512 + kk);
                else         bf = *reinterpret_cast<const bf16x8*>(WT0  + (size_t)n * 1024 + (kk - 512));
                acc[q] = __builtin_amdgcn_mfma_f32_16x16x32_bf16(a, bf, acc[q], 0, 0, 0);
            }
        }
        const int ncol = hc + r16;
        #pragma unroll
        for (int r = 0; r < 4; ++r) {
            const int b = wave * 16 + kg * 4 + r;     // D row = batch
            float gi = acc[0][r] + b0[ncol];
            float gf = acc[1][r] + b0[H_ + ncol];
            float gg = acc[2][r] + b0[2 * H_ + ncol];
            float go = acc[3][r] + b0[3 * H_ + ncol];
            const int idx = b * H_ + ncol;
            float cold = c0[idx];
            float cn = sigm(gf) * cold + sigm(gi) * ftanh(gg);
            float hn = sigm(go) * ftanh(cn);
            c0[idx] = cn;
            h0cur[idx] = f2bf(hn);
            if (p == T_ - 1) {                        // final c0, h0 (fp32)
                out[BTH + idx] = cn;
                out[BTH + BH + idx] = hn;
            }
        }
    } else {
        if (p < 1) return;
        const int t = p - 1;
        const int hc = (bid - 64) * 16;               // h1 columns
        const u16* h0in   = h0b + ((p + 1) & 1) * BH; // h0[t] (written last phase)
        const u16* h1prev = h1b + (p & 1) * BH;       // h1[t-1]
        u16*       h1cur  = h1b + ((p + 1) & 1) * BH; // h1[t]
        const int brow = wave * 16 + r16;

        for (int ks = 0; ks < 64; ++ks) {
            const int kk = ks * 32 + kg * 8;          // k within [0,2048)
            bf16x8 a;
            if (ks < 32) a = *reinterpret_cast<const bf16x8*>(h0in   + brow * H_ + kk);
            else         a = *reinterpret_cast<const bf16x8*>(h1prev + brow * H_ + (kk - 1024));
            #pragma unroll
            for (int q = 0; q < 4; ++q) {
                const int n = q * H_ + hc + r16;
                bf16x8 bf = *reinterpret_cast<const bf16x8*>(WT1 + (size_t)n * 2048 + kk);
                acc[q] = __builtin_amdgcn_mfma_f32_16x16x32_bf16(a, bf, acc[q], 0, 0, 0);
            }
        }
        const int ncol = hc + r16;
        #pragma unroll
        for (int r = 0; r < 4; ++r) {
            const int b = wave * 16 + kg * 4 + r;
            float gi = acc[0][r] + b1[ncol];
            float gf = acc[1][r] + b1[H_ + ncol];
            float gg = acc[2][r] + b1[2 * H_ + ncol];
            float go = acc[3][r] + b1[3 * H_ + ncol];
            const int idx = b * H_ + ncol;
            float cold = c1[idx];
            float cn = sigm(gf) * cold + sigm(gi) * ftanh(gg);
            float hn = sigm(go) * ftanh(cn);
            c1[idx] = cn;
            h1cur[idx] = f2bf(hn);
            out[(size_t)b * (T_ * H_) + (size_t)t * H_ + ncol] = hn;  // y
            if (p == T_) {                            // final c1, h1 (fp32)
                out[BTH + 2 * BH + idx] = cn;
                out[BTH + 3 * BH + idx] = hn;
            }
        }
    }
}

extern "C" void kernel_launch(void* const* d_in, const int* in_sizes, int n_in,
                              void* d_out, int out_size, void* d_ws, size_t ws_size,
                              hipStream_t stream) {
    const float* x   = (const float*)d_in[0];
    const float* Wx0 = (const float*)d_in[1];
    const float* Wh0 = (const float*)d_in[2];
    const float* b0  = (const float*)d_in[3];
    const float* Wx1 = (const float*)d_in[4];
    const float* Wh1 = (const float*)d_in[5];
    const float* b1  = (const float*)d_in[6];
    float* out = (float*)d_out;
    char* ws = (char*)d_ws;

    // workspace layout (bytes)
    u16* xb   = (u16*)(ws);               // 64*1024*512*2  = 67,108,864
    u16* Wx0T = (u16*)(ws + 67108864);    // 4096*512*2     =  4,194,304
    u16* WT0  = (u16*)(ws + 71303168);    // 4096*1024*2    =  8,388,608
    u16* WT1  = (u16*)(ws + 79691776);    // 4096*2048*2    = 16,777,216
    u16* h0b  = (u16*)(ws + 96468992);    // 2*64*1024*2    =    262,144
    u16* h1b  = (u16*)(ws + 96731136);    // 2*64*1024*2    =    262,144
    float* c0 = (float*)(ws + 96993280);  // 64*1024*4      =    262,144
    float* c1 = (float*)(ws + 97255424);  // 64*1024*4      =    262,144

    // zero h double-buffers + cell states (contiguous 1 MiB)
    hipMemsetAsync(ws + 96468992, 0, 1048576, stream);

    pack_x<<<16384, 256, 0, stream>>>(x, xb);
    dim3 blk(32, 8);
    transp<<<dim3(128, 16), blk, 0, stream>>>(Wx0, Wx0T, 4096, 512, 0);
    transp<<<dim3(128, 32), blk, 0, stream>>>(Wh0, WT0, 4096, 1024, 0);
    transp<<<dim3(128, 32), blk, 0, stream>>>(Wx1, WT1, 4096, 2048, 0);
    transp<<<dim3(128, 32), blk, 0, stream>>>(Wh1, WT1, 4096, 2048, 1024);

    for (int p = 0; p <= T_; ++p)
        lstm_phase<<<128, 256, 0, stream>>>(xb, Wx0T, WT0, WT1, b0, b1,
                                            h0b, h1b, c0, c1, out, p);
}

// Round 3
// 25967.575 us; speedup vs baseline: 1.6592x; 1.6592x over previous
//
#include <hip/hip_runtime.h>
#include <hip/hip_bf16.h>
#include <cstdint>

#define B_ 64
#define T_ 1024
#define D_ 512
#define H_ 1024

typedef unsigned short u16;
typedef __attribute__((ext_vector_type(4))) float f32x4;
typedef __attribute__((ext_vector_type(8))) short bf16x8;   // 8 bf16 in 4 VGPRs
typedef __attribute__((ext_vector_type(8))) u16 u16x8;

__device__ __forceinline__ u16 f2bf(float f) {
    uint32_t u = __float_as_uint(f);
    uint32_t r = (u + 0x7FFFu + ((u >> 16) & 1u)) >> 16;   // RNE
    return (u16)r;
}
__device__ __forceinline__ float sigm(float x)  { return 1.f / (1.f + __expf(-x)); }
__device__ __forceinline__ float ftanh(float x) { return 1.f - 2.f / (__expf(2.f * x) + 1.f); }

// ---- x fp32 -> bf16 (vectorized) ----
__global__ __launch_bounds__(256) void pack_x(const float* __restrict__ x, u16* __restrict__ xb) {
    size_t i = ((size_t)blockIdx.x * 256 + threadIdx.x) * 8;
    float4 a = *reinterpret_cast<const float4*>(x + i);
    float4 c = *reinterpret_cast<const float4*>(x + i + 4);
    u16x8 v;
    v[0] = f2bf(a.x); v[1] = f2bf(a.y); v[2] = f2bf(a.z); v[3] = f2bf(a.w);
    v[4] = f2bf(c.x); v[5] = f2bf(c.y); v[6] = f2bf(c.z); v[7] = f2bf(c.w);
    *reinterpret_cast<u16x8*>(xb + i) = v;
}

// ---- W [K][N] fp32 -> WT [N][dstLD] bf16 at column offset koff ----
__global__ __launch_bounds__(256) void transp(const float* __restrict__ src, u16* __restrict__ dst,
                                              int N, int dstLD, int koff) {
    __shared__ float tile[32][33];
    int n0 = blockIdx.x * 32, k0 = blockIdx.y * 32;
    int tx = threadIdx.x, ty = threadIdx.y;   // 32 x 8
    #pragma unroll
    for (int i = 0; i < 4; ++i)
        tile[ty + 8 * i][tx] = src[(size_t)(k0 + ty + 8 * i) * N + n0 + tx];
    __syncthreads();
    #pragma unroll
    for (int i = 0; i < 4; ++i) {
        int n = n0 + ty + 8 * i;
        dst[(size_t)n * dstLD + koff + k0 + tx] = f2bf(tile[tx][ty + 8 * i]);
    }
}

// ============ persistent fused 2-layer LSTM ============
// 256 blocks x 512 threads, 1 block/CU.
// blocks 0..127 : layer0, h-cols [8b, 8b+8), weights [Wx0;Wh0] slice in LDS (96 KB), K=1536
// blocks 128..255: layer1, h-cols [8(b-128),..+8), weights [Wx1;Wh1] slice (128 KB), K=2048
// LDS col c in [0,32): gate g=c&3, h-col h=c>>2  (so pointwise reads gates as float4)
// waves: wave = kh*4 + m ; m = M-tile (16 batch rows), kh = K-half. K-reduce via LDS scratch.
// grid barrier: monotone atomic counter, agent scope.
extern "C" __global__ void __launch_bounds__(512, 2) lstm_persist(
    const u16* __restrict__ xb, const u16* __restrict__ Wx0T,
    const u16* __restrict__ WT0, const u16* __restrict__ WT1,
    const float* __restrict__ b0, const float* __restrict__ b1,
    u16* __restrict__ h0b, u16* __restrict__ h1b,
    float* __restrict__ out, unsigned int* __restrict__ bar)
{
    extern __shared__ char lds[];
    const int tid = threadIdx.x;
    const int bid = blockIdx.x;
    const bool isL1 = bid >= 128;
    const int bh = (isL1 ? bid - 128 : bid) * 8;   // first owned h-col
    const int KL = isL1 ? 2048 : 1536;
    const int K2 = KL * 2;                          // LDS col stride (bytes)
    float* scr = (float*)(lds + 32 * K2);           // [2][64][36] f32 partial gates

    // ---- stage weight slice into LDS (XOR-swizzled for conflict-free frag reads) ----
    const int KO = KL / 8;
    for (int idx = tid; idx < 32 * KO; idx += 512) {
        const int c = idx / KO, ko = idx - c * KO;
        const int g = c & 3, h = c >> 2;
        const int n = g * H_ + bh + h;              // global gate-col (flax order i,f,g,o)
        const int k = ko * 8;
        u16x8 v;
        if (isL1)            v = *reinterpret_cast<const u16x8*>(WT1  + (size_t)n * 2048 + k);
        else if (k < 512)    v = *reinterpret_cast<const u16x8*>(Wx0T + (size_t)n * 512  + k);
        else                 v = *reinterpret_cast<const u16x8*>(WT0  + (size_t)n * 1024 + (k - 512));
        int byte = c * K2 + k * 2;
        byte ^= ((c & 7) << 4);
        *reinterpret_cast<u16x8*>(lds + byte) = v;
    }

    const int wave = tid >> 6, lane = tid & 63;
    const int r16 = lane & 15, kg = lane >> 4;
    const int m  = wave & 3;        // M-tile
    const int kh = wave >> 2;       // K-half
    const int rowA = m * 16 + r16;  // batch row this lane loads for A
    const int prow = tid >> 3, ph = tid & 7;   // pointwise ownership: (row, h-col)

    float bv0, bv1, bv2, bv3;
    {
        const float* bias = isL1 ? b1 : b0;
        bv0 = bias[bh + ph];          bv1 = bias[H_ + bh + ph];
        bv2 = bias[2 * H_ + bh + ph]; bv3 = bias[3 * H_ + bh + ph];
    }
    float creg = 0.f;                // cell state lives in registers

    const int BH = B_ * H_;
    const size_t BTH = (size_t)B_ * T_ * H_;
    const int sw = ((r16 & 7) << 4);
    const int kbase = kg * 8;

    __syncthreads();   // weights staged

    for (int p = 0; p <= T_; ++p) {
        const bool active = isL1 ? (p >= 1) : (p < T_);
        if (active) {
            f32x4 acc0 = {0.f, 0.f, 0.f, 0.f}, acc1 = {0.f, 0.f, 0.f, 0.f};
            if (isL1) {
                // A = [h0[t] ; h1[t-1]], K-half kh
                const u16* A = (kh == 0) ? (h0b + ((p - 1) & 1) * BH)
                                         : (h1b + (p & 1) * BH);
                const u16* arow = A + rowA * H_;
                #pragma unroll 8
                for (int ks = 0; ks < 32; ++ks) {
                    const int k = ks * 32 + kbase;           // within the half
                    bf16x8 a = *reinterpret_cast<const bf16x8*>(arow + k);
                    const int kb = (kh * 1024 + k) * 2;
                    bf16x8 w0 = *reinterpret_cast<const bf16x8*>(lds + ((r16 * K2 + kb) ^ sw));
                    bf16x8 w1 = *reinterpret_cast<const bf16x8*>(lds + (((r16 + 16) * K2 + kb) ^ sw));
                    acc0 = __builtin_amdgcn_mfma_f32_16x16x32_bf16(a, w0, acc0, 0, 0, 0);
                    acc1 = __builtin_amdgcn_mfma_f32_16x16x32_bf16(a, w1, acc1, 0, 0, 0);
                }
            } else {
                // A = [x_t ; h0[p-1]], K-half kh (24 k-slices each)
                const u16* h0prev = h0b + ((p + 1) & 1) * BH;
                const u16* xrow = xb + ((size_t)rowA * T_ + p) * D_;
                const u16* hrow = h0prev + rowA * H_;
                const int s0 = kh * 24;
                #pragma unroll 8
                for (int ks = s0; ks < s0 + 24; ++ks) {
                    const int k = ks * 32 + kbase;           // global k in [0,1536)
                    bf16x8 a = (ks < 16) ? *reinterpret_cast<const bf16x8*>(xrow + k)
                                         : *reinterpret_cast<const bf16x8*>(hrow + (k - 512));
                    const int kb = k * 2;
                    bf16x8 w0 = *reinterpret_cast<const bf16x8*>(lds + ((r16 * K2 + kb) ^ sw));
                    bf16x8 w1 = *reinterpret_cast<const bf16x8*>(lds + (((r16 + 16) * K2 + kb) ^ sw));
                    acc0 = __builtin_amdgcn_mfma_f32_16x16x32_bf16(a, w0, acc0, 0, 0, 0);
                    acc1 = __builtin_amdgcn_mfma_f32_16x16x32_bf16(a, w1, acc1, 0, 0, 0);
                }
            }
            #pragma unroll
            for (int r = 0; r < 4; ++r) {
                const int row = m * 16 + kg * 4 + r;         // D layout: col=lane&15, row=kg*4+r
                scr[(kh * 64 + row) * 36 + r16]      = acc0[r];
                scr[(kh * 64 + row) * 36 + 16 + r16] = acc1[r];
            }
        }
        __syncthreads();
        if (active) {
            const int t = isL1 ? p - 1 : p;
            const float4 ga = *reinterpret_cast<const float4*>(&scr[prow * 36 + 4 * ph]);
            const float4 gb = *reinterpret_cast<const float4*>(&scr[(64 + prow) * 36 + 4 * ph]);
            const float gi = ga.x + gb.x + bv0;
            const float gf = ga.y + gb.y + bv1;
            const float gg = ga.z + gb.z + bv2;
            const float go = ga.w + gb.w + bv3;
            const float cn = sigm(gf) * creg + sigm(gi) * ftanh(gg);
            const float hn = sigm(go) * ftanh(cn);
            creg = cn;
            const u16 hb = f2bf(hn);
            const int hidx = prow * H_ + bh + ph;
            if (isL1) {
                h1b[((p - 1) & 1) * BH + hidx] = hb;
                out[((size_t)prow * T_ + t) * H_ + bh + ph] = hn;    // y
                if (p == T_) {
                    out[BTH + 2 * BH + hidx] = cn;                   // c1
                    out[BTH + 3 * BH + hidx] = hn;                   // h1
                }
            } else {
                h0b[(p & 1) * BH + hidx] = hb;
                if (p == T_ - 1) {
                    out[BTH + hidx] = cn;                            // c0
                    out[BTH + BH + hidx] = hn;                       // h0
                }
            }
        }
        // ---- grid barrier (monotone counter, agent scope) ----
        __syncthreads();
        if (tid == 0) {
            __hip_atomic_fetch_add(bar, 1u, __ATOMIC_ACQ_REL, __HIP_MEMORY_SCOPE_AGENT);
            const unsigned int tgt = (unsigned int)(p + 1) * 256u;
            while (__hip_atomic_load(bar, __ATOMIC_RELAXED, __HIP_MEMORY_SCOPE_AGENT) < tgt)
                __builtin_amdgcn_s_sleep(2);
            __builtin_amdgcn_fence(__ATOMIC_ACQUIRE, "agent");
        }
        __syncthreads();
    }
}

extern "C" void kernel_launch(void* const* d_in, const int* in_sizes, int n_in,
                              void* d_out, int out_size, void* d_ws, size_t ws_size,
                              hipStream_t stream) {
    const float* x   = (const float*)d_in[0];
    const float* Wx0 = (const float*)d_in[1];
    const float* Wh0 = (const float*)d_in[2];
    const float* b0  = (const float*)d_in[3];
    const float* Wx1 = (const float*)d_in[4];
    const float* Wh1 = (const float*)d_in[5];
    const float* b1  = (const float*)d_in[6];
    float* out = (float*)d_out;
    char* ws = (char*)d_ws;

    // workspace layout (bytes)
    u16* xb   = (u16*)(ws);               // 67,108,864
    u16* Wx0T = (u16*)(ws + 67108864);    //  4,194,304
    u16* WT0  = (u16*)(ws + 71303168);    //  8,388,608
    u16* WT1  = (u16*)(ws + 79691776);    // 16,777,216
    u16* h0b  = (u16*)(ws + 96468992);    //    262,144 (2 buffers)
    u16* h1b  = (u16*)(ws + 96731136);    //    262,144 (2 buffers)
    unsigned int* bar = (unsigned int*)(ws + 96993280); // 256

    const int LDS_BYTES = 32 * 2048 * 2 + 2 * 64 * 36 * 4;   // 149,504
    (void)hipFuncSetAttribute((const void*)lstm_persist,
                        hipFuncAttributeMaxDynamicSharedMemorySize, LDS_BYTES);

    // zero h double-buffers + barrier counter
    (void)hipMemsetAsync(ws + 96468992, 0, 262144 * 2 + 256, stream);

    pack_x<<<16384, 256, 0, stream>>>(x, xb);
    dim3 blk(32, 8);
    transp<<<dim3(128, 16), blk, 0, stream>>>(Wx0, Wx0T, 4096, 512, 0);
    transp<<<dim3(128, 32), blk, 0, stream>>>(Wh0, WT0, 4096, 1024, 0);
    transp<<<dim3(128, 32), blk, 0, stream>>>(Wx1, WT1, 4096, 2048, 0);
    transp<<<dim3(128, 32), blk, 0, stream>>>(Wh1, WT1, 4096, 2048, 1024);

    lstm_persist<<<256, 512, LDS_BYTES, stream>>>(xb, Wx0T, WT0, WT1, b0, b1,
                                                  h0b, h1b, out, bar);
}